// Round 1
// baseline (6182.613 us; speedup 1.0000x reference)
//
#include <hip/hip_runtime.h>
#include <hip/hip_bf16.h>

typedef __bf16 bf16_t;
typedef bf16_t bf16x8 __attribute__((ext_vector_type(8)));
typedef float f32x4 __attribute__((ext_vector_type(4)));

#define N_ROWS 4096
#define DIM    2048
#define VOCAB  65536
#define IGN    (-100)

#define BM 128
#define BN 128
#define BK 64
#define NK (DIM / BK)
#define THREADS 512

// ---------------------------------------------------------------------------
// Kernel 1: tiled bf16 MFMA GEMM over (row-tile, vocab-tile); per-row partial
// sum of exp(logit) accumulated into ws_sumexp via atomicAdd (no max shift:
// logits ~ N(0,1), sum < 3e7, fp32-safe).
// ---------------------------------------------------------------------------
__global__ __launch_bounds__(THREADS, 4)
void lce_gemm(const float* __restrict__ E, const float* __restrict__ C,
              float* __restrict__ sumexp) {
  extern __shared__ unsigned char lds[];  // [2 buf][A 16KB | B 16KB] = 64KB
  const int tid  = threadIdx.x;
  const int brow = blockIdx.y * BM;
  const int bcol = blockIdx.x * BN;

  float4 ra[4], rb[4];

  auto ld = [&](int k0) {
#pragma unroll
    for (int i = 0; i < 4; ++i) {
      int f = tid + i * THREADS;          // float4 index, 2048 per tile
      int r = f >> 4;                     // 16 float4 per row (BK=64 floats)
      int c = (f & 15) << 2;              // float col
      ra[i] = *reinterpret_cast<const float4*>(&E[(size_t)(brow + r) * DIM + k0 + c]);
      rb[i] = *reinterpret_cast<const float4*>(&C[(size_t)(bcol + r) * DIM + k0 + c]);
    }
  };

  auto st = [&](int buf) {
    unsigned char* a = lds + buf * 32768;
    unsigned char* b = a + 16384;
#pragma unroll
    for (int i = 0; i < 4; ++i) {
      int f  = tid + i * THREADS;
      int r  = f >> 4;
      int cb = (f & 15) << 3;             // byte col of the 8-byte bf16x4 group
      int off = r * 128 + (cb ^ ((r & 7) << 4));  // XOR swizzle
      union { bf16_t h[4]; unsigned long long u; } pa, pb;
      pa.h[0] = (bf16_t)ra[i].x; pa.h[1] = (bf16_t)ra[i].y;
      pa.h[2] = (bf16_t)ra[i].z; pa.h[3] = (bf16_t)ra[i].w;
      pb.h[0] = (bf16_t)rb[i].x; pb.h[1] = (bf16_t)rb[i].y;
      pb.h[2] = (bf16_t)rb[i].z; pb.h[3] = (bf16_t)rb[i].w;
      *reinterpret_cast<unsigned long long*>(a + off) = pa.u;
      *reinterpret_cast<unsigned long long*>(b + off) = pb.u;
    }
  };

  f32x4 acc[4][2];
#pragma unroll
  for (int mi = 0; mi < 4; ++mi)
#pragma unroll
    for (int ni = 0; ni < 2; ++ni)
      acc[mi][ni] = (f32x4){0.f, 0.f, 0.f, 0.f};

  const int lane = tid & 63, wid = tid >> 6;
  const int wr = wid >> 2, wc = wid & 3;  // 2x4 wave grid; wave owns 64x32
  const int l15 = lane & 15, lg = lane >> 4;
  const int swz = (l15 & 7) << 4;         // row&7 == l15&7 for frag rows

  auto comp = [&](int buf) {
    const unsigned char* a = lds + buf * 32768;
    const unsigned char* b = a + 16384;
#pragma unroll
    for (int kk = 0; kk < 2; ++kk) {
      const int cbase = (kk * 64 + lg * 16) ^ swz;
      bf16x8 af[4], bfr[2];
#pragma unroll
      for (int mi = 0; mi < 4; ++mi) {
        int row = wr * 64 + mi * 16 + l15;
        af[mi] = *reinterpret_cast<const bf16x8*>(a + row * 128 + cbase);
      }
#pragma unroll
      for (int ni = 0; ni < 2; ++ni) {
        int row = wc * 32 + ni * 16 + l15;
        bfr[ni] = *reinterpret_cast<const bf16x8*>(b + row * 128 + cbase);
      }
#pragma unroll
      for (int mi = 0; mi < 4; ++mi)
#pragma unroll
        for (int ni = 0; ni < 2; ++ni)
          acc[mi][ni] = __builtin_amdgcn_mfma_f32_16x16x32_bf16(
              af[mi], bfr[ni], acc[mi][ni], 0, 0, 0);
    }
  };

  ld(0);
  st(0);
  for (int kt = 0; kt < NK; ++kt) {
    __syncthreads();
    if (kt + 1 < NK) ld((kt + 1) * BK);
    comp(kt & 1);
    if (kt + 1 < NK) st((kt + 1) & 1);
  }

  // Epilogue: per-row sum of exp over this block's 128 vocab cols.
  // C/D layout: col = lane&15, row(frag) = lg*4 + j.
#pragma unroll
  for (int mi = 0; mi < 4; ++mi) {
    float p[4];
#pragma unroll
    for (int j = 0; j < 4; ++j)
      p[j] = __expf(acc[mi][0][j]) + __expf(acc[mi][1][j]);
#pragma unroll
    for (int m = 1; m < 16; m <<= 1) {
#pragma unroll
      for (int j = 0; j < 4; ++j)
        p[j] += __shfl_xor(p[j], m, 64);
    }
    if (l15 == 0) {
      int row = brow + wr * 64 + mi * 16 + lg * 4;
#pragma unroll
      for (int j = 0; j < 4; ++j)
        atomicAdd(&sumexp[row + j], p[j]);
    }
  }
}

// ---------------------------------------------------------------------------
// Kernel 2: exact fp32 target logit, one wave per row.
// ---------------------------------------------------------------------------
__global__ __launch_bounds__(256)
void lce_tgt(const float* __restrict__ E, const float* __restrict__ C,
             const int* __restrict__ T, float* __restrict__ tgt) {
  int w = (int)((blockIdx.x * blockDim.x + threadIdx.x) >> 6);
  int lane = threadIdx.x & 63;
  if (w >= N_ROWS) return;
  int t = T[w];
  float s = 0.f;
  if (t != IGN) {
    const float4* er = reinterpret_cast<const float4*>(E + (size_t)w * DIM);
    const float4* cr = reinterpret_cast<const float4*>(C + (size_t)t * DIM);
#pragma unroll
    for (int i = 0; i < DIM / 4 / 64; ++i) {
      float4 a = er[lane + i * 64];
      float4 b = cr[lane + i * 64];
      s = fmaf(a.x, b.x, s); s = fmaf(a.y, b.y, s);
      s = fmaf(a.z, b.z, s); s = fmaf(a.w, b.w, s);
    }
#pragma unroll
    for (int m = 1; m < 64; m <<= 1) s += __shfl_xor(s, m, 64);
  }
  if (lane == 0) tgt[w] = s;
}

// ---------------------------------------------------------------------------
// Kernel 3: final scalar reduce: mean over valid rows of (log(sumexp) - tgt).
// ---------------------------------------------------------------------------
__global__ __launch_bounds__(256)
void lce_finalize(const float* __restrict__ sumexp, const float* __restrict__ tgt,
                  const int* __restrict__ T, float* __restrict__ out) {
  int tid = threadIdx.x;
  float nll = 0.f, cnt = 0.f;
  for (int n = tid; n < N_ROWS; n += 256) {
    if (T[n] != IGN) {
      nll += logf(sumexp[n]) - tgt[n];
      cnt += 1.f;
    }
  }
#pragma unroll
  for (int m = 1; m < 64; m <<= 1) {
    nll += __shfl_xor(nll, m, 64);
    cnt += __shfl_xor(cnt, m, 64);
  }
  __shared__ float sn[4], sc[4];
  if ((tid & 63) == 0) { sn[tid >> 6] = nll; sc[tid >> 6] = cnt; }
  __syncthreads();
  if (tid == 0) {
    float a = 0.f, b = 0.f;
#pragma unroll
    for (int i = 0; i < 4; ++i) { a += sn[i]; b += sc[i]; }
    out[0] = a / fmaxf(b, 1.f);
  }
}

extern "C" void kernel_launch(void* const* d_in, const int* in_sizes, int n_in,
                              void* d_out, int out_size, void* d_ws, size_t ws_size,
                              hipStream_t stream) {
  const float* E = (const float*)d_in[0];
  const float* C = (const float*)d_in[1];
  const int*   T = (const int*)d_in[2];
  float* out = (float*)d_out;

  float* sumexp = (float*)d_ws;            // N_ROWS floats
  float* tgt    = sumexp + N_ROWS;         // N_ROWS floats

  hipMemsetAsync(sumexp, 0, N_ROWS * sizeof(float), stream);

  dim3 ggrid(VOCAB / BN, N_ROWS / BM);
  lce_gemm<<<ggrid, THREADS, 65536, stream>>>(E, C, sumexp);

  lce_tgt<<<dim3((N_ROWS * 64) / 256), 256, 0, stream>>>(E, C, T, tgt);

  lce_finalize<<<dim3(1), 256, 0, stream>>>(sumexp, tgt, T, out);
}

// Round 4
// 1381.738 us; speedup vs baseline: 4.4745x; 4.4745x over previous
//
#include <hip/hip_runtime.h>
#include <hip/hip_bf16.h>

typedef __bf16 bf16_t;
typedef bf16_t bf16x8 __attribute__((ext_vector_type(8)));
typedef float f32x4 __attribute__((ext_vector_type(4)));

#define N_ROWS 4096
#define DIM    2048
#define VOCAB  65536
#define IGN    (-100)

// ---------------- fast path (bf16, m97 structure) --------------------------
#define BM 128
#define BN 128
#define BK 32
#define NKT (DIM / BK)   // 64

#define GLOAD_LDS16(gp, lp)                                                  \
  __builtin_amdgcn_global_load_lds(                                          \
      (const __attribute__((address_space(1))) void*)(gp),                   \
      (__attribute__((address_space(3))) void*)(lp), 16, 0, 0)

// fp32 -> bf16 pre-convert, 8 elems/thread/iter
__global__ __launch_bounds__(256)
void cvt_bf16(const float* __restrict__ src, bf16_t* __restrict__ dst, long n8) {
  long i = (long)blockIdx.x * 256 + threadIdx.x;
  long stride = (long)gridDim.x * 256;
  for (; i < n8; i += stride) {
    const float4* s = reinterpret_cast<const float4*>(src) + i * 2;
    float4 a = s[0], b = s[1];
    bf16x8 v = {(bf16_t)a.x, (bf16_t)a.y, (bf16_t)a.z, (bf16_t)a.w,
                (bf16_t)b.x, (bf16_t)b.y, (bf16_t)b.z, (bf16_t)b.w};
    *reinterpret_cast<bf16x8*>(dst + i * 8) = v;
  }
}

// 128x128 tile, BK=32, 4 waves (2x2, 64x64 each), global_load_lds staging,
// double-buffered linear LDS, one barrier per K-step (m97 structure).
__global__ __launch_bounds__(256, 3)
void lce_gemm_bf(const bf16_t* __restrict__ Eb, const bf16_t* __restrict__ Cb,
                 float* __restrict__ sumexp) {
  __shared__ unsigned char lds[2 * 16384];  // [buf][A 8K | B 8K]
  const int tid  = threadIdx.x;
  const int brow = blockIdx.x * BM;   // row-tile = FAST dim (C-tile reuse)
  const int bcol = blockIdx.y * BN;

  const int r4 = tid >> 2;            // 0..63
  const int cb = (tid & 3) << 4;      // byte col 0..48
  const int ccol = (tid & 3) << 3;    // bf16 col 0..24

  auto stage = [&](int buf, int kt) {
    unsigned char* base = lds + buf * 16384;
    const int k0 = kt * BK;
#pragma unroll
    for (int i = 0; i < 2; ++i) {
      int row = r4 + i * 64;
      GLOAD_LDS16(Eb + (size_t)(brow + row) * DIM + k0 + ccol,
                  base + row * 64 + cb);
    }
#pragma unroll
    for (int i = 0; i < 2; ++i) {
      int row = r4 + i * 64;
      GLOAD_LDS16(Cb + (size_t)(bcol + row) * DIM + k0 + ccol,
                  base + 8192 + row * 64 + cb);
    }
  };

  f32x4 acc[4][4];
#pragma unroll
  for (int mi = 0; mi < 4; ++mi)
#pragma unroll
    for (int ni = 0; ni < 4; ++ni)
      acc[mi][ni] = (f32x4){0.f, 0.f, 0.f, 0.f};

  const int lane = tid & 63, wid = tid >> 6;
  const int wr = wid >> 1, wc = wid & 1;   // 2x2 waves, each 64x64 out
  const int l15 = lane & 15, lg = lane >> 4;

  auto comp = [&](int buf) {
    const unsigned char* a = lds + buf * 16384;
    const unsigned char* b = a + 8192;
    bf16x8 af[4], bfr[4];
#pragma unroll
    for (int mi = 0; mi < 4; ++mi)
      af[mi] = *reinterpret_cast<const bf16x8*>(
          a + (wr * 64 + mi * 16 + l15) * 64 + lg * 16);
#pragma unroll
    for (int ni = 0; ni < 4; ++ni)
      bfr[ni] = *reinterpret_cast<const bf16x8*>(
          b + (wc * 64 + ni * 16 + l15) * 64 + lg * 16);
#pragma unroll
    for (int mi = 0; mi < 4; ++mi)
#pragma unroll
      for (int ni = 0; ni < 4; ++ni)
        acc[mi][ni] = __builtin_amdgcn_mfma_f32_16x16x32_bf16(
            af[mi], bfr[ni], acc[mi][ni], 0, 0, 0);
  };

  stage(0, 0);
  for (int kt = 0; kt < NKT; ++kt) {
    __syncthreads();                       // drains vmcnt -> buf[kt&1] ready
    if (kt + 1 < NKT) stage((kt + 1) & 1, kt + 1);
    comp(kt & 1);
  }

  // Epilogue: per-row sum of exp over this block's 128 vocab cols.
  // C/D layout: col = l15, row(frag) = lg*4 + j.
#pragma unroll
  for (int mi = 0; mi < 4; ++mi) {
    float p[4];
#pragma unroll
    for (int j = 0; j < 4; ++j) {
      p[j] = 0.f;
#pragma unroll
      for (int ni = 0; ni < 4; ++ni) p[j] += __expf(acc[mi][ni][j]);
    }
#pragma unroll
    for (int m = 1; m < 16; m <<= 1)
#pragma unroll
      for (int j = 0; j < 4; ++j) p[j] += __shfl_xor(p[j], m, 64);
    if (l15 == 0) {
      int row = brow + wr * 64 + mi * 16 + lg * 4;
#pragma unroll
      for (int j = 0; j < 4; ++j) atomicAdd(&sumexp[row + j], p[j]);
    }
  }
}

// ---------------- fallback path (fp32 reg-staged, fixed grid order) --------
#define FBK 64
#define FNK (DIM / FBK)
#define FTHREADS 512

__global__ __launch_bounds__(FTHREADS, 4)
void lce_gemm_f32(const float* __restrict__ E, const float* __restrict__ C,
                  float* __restrict__ sumexp) {
  extern __shared__ unsigned char lds[];
  const int tid  = threadIdx.x;
  const int brow = blockIdx.x * BM;   // row-tile fast
  const int bcol = blockIdx.y * BN;

  float4 ra[4], rb[4];
  auto ld = [&](int k0) {
#pragma unroll
    for (int i = 0; i < 4; ++i) {
      int f = tid + i * FTHREADS;
      int r = f >> 4;
      int c = (f & 15) << 2;
      ra[i] = *reinterpret_cast<const float4*>(&E[(size_t)(brow + r) * DIM + k0 + c]);
      rb[i] = *reinterpret_cast<const float4*>(&C[(size_t)(bcol + r) * DIM + k0 + c]);
    }
  };
  auto st = [&](int buf) {
    unsigned char* a = lds + buf * 32768;
    unsigned char* b = a + 16384;
#pragma unroll
    for (int i = 0; i < 4; ++i) {
      int f  = tid + i * FTHREADS;
      int r  = f >> 4;
      int cbb = (f & 15) << 3;
      int off = r * 128 + (cbb ^ ((r & 7) << 4));
      union { bf16_t h[4]; unsigned long long u; } pa, pb;
      pa.h[0] = (bf16_t)ra[i].x; pa.h[1] = (bf16_t)ra[i].y;
      pa.h[2] = (bf16_t)ra[i].z; pa.h[3] = (bf16_t)ra[i].w;
      pb.h[0] = (bf16_t)rb[i].x; pb.h[1] = (bf16_t)rb[i].y;
      pb.h[2] = (bf16_t)rb[i].z; pb.h[3] = (bf16_t)rb[i].w;
      *reinterpret_cast<unsigned long long*>(a + off) = pa.u;
      *reinterpret_cast<unsigned long long*>(b + off) = pb.u;
    }
  };

  f32x4 acc[4][2];
#pragma unroll
  for (int mi = 0; mi < 4; ++mi)
#pragma unroll
    for (int ni = 0; ni < 2; ++ni) acc[mi][ni] = (f32x4){0.f, 0.f, 0.f, 0.f};

  const int lane = tid & 63, wid = tid >> 6;
  const int wr = wid >> 2, wc = wid & 3;
  const int l15 = lane & 15, lg = lane >> 4;
  const int swz = (l15 & 7) << 4;

  auto comp = [&](int buf) {
    const unsigned char* a = lds + buf * 32768;
    const unsigned char* b = a + 16384;
#pragma unroll
    for (int kk = 0; kk < 2; ++kk) {
      const int cbase = (kk * 64 + lg * 16) ^ swz;
      bf16x8 af[4], bfr[2];
#pragma unroll
      for (int mi = 0; mi < 4; ++mi)
        af[mi] = *reinterpret_cast<const bf16x8*>(
            a + (wr * 64 + mi * 16 + l15) * 128 + cbase);
#pragma unroll
      for (int ni = 0; ni < 2; ++ni)
        bfr[ni] = *reinterpret_cast<const bf16x8*>(
            b + (wc * 32 + ni * 16 + l15) * 128 + cbase);
#pragma unroll
      for (int mi = 0; mi < 4; ++mi)
#pragma unroll
        for (int ni = 0; ni < 2; ++ni)
          acc[mi][ni] = __builtin_amdgcn_mfma_f32_16x16x32_bf16(
              af[mi], bfr[ni], acc[mi][ni], 0, 0, 0);
    }
  };

  ld(0);
  st(0);
  for (int kt = 0; kt < FNK; ++kt) {
    __syncthreads();
    if (kt + 1 < FNK) ld((kt + 1) * FBK);
    comp(kt & 1);
    if (kt + 1 < FNK) st((kt + 1) & 1);
  }

#pragma unroll
  for (int mi = 0; mi < 4; ++mi) {
    float p[4];
#pragma unroll
    for (int j = 0; j < 4; ++j)
      p[j] = __expf(acc[mi][0][j]) + __expf(acc[mi][1][j]);
#pragma unroll
    for (int m = 1; m < 16; m <<= 1)
#pragma unroll
      for (int j = 0; j < 4; ++j) p[j] += __shfl_xor(p[j], m, 64);
    if (l15 == 0) {
      int row = brow + wr * 64 + mi * 16 + lg * 4;
#pragma unroll
      for (int j = 0; j < 4; ++j) atomicAdd(&sumexp[row + j], p[j]);
    }
  }
}

// ---------------- exact fp32 target logit, one wave per row ----------------
__global__ __launch_bounds__(256)
void lce_tgt(const float* __restrict__ E, const float* __restrict__ C,
             const int* __restrict__ T, float* __restrict__ tgt) {
  int w = (int)((blockIdx.x * blockDim.x + threadIdx.x) >> 6);
  int lane = threadIdx.x & 63;
  if (w >= N_ROWS) return;
  int t = T[w];
  float s = 0.f;
  if (t != IGN) {
    const float4* er = reinterpret_cast<const float4*>(E + (size_t)w * DIM);
    const float4* cr = reinterpret_cast<const float4*>(C + (size_t)t * DIM);
#pragma unroll
    for (int i = 0; i < DIM / 4 / 64; ++i) {
      float4 a = er[lane + i * 64];
      float4 b = cr[lane + i * 64];
      s = fmaf(a.x, b.x, s); s = fmaf(a.y, b.y, s);
      s = fmaf(a.z, b.z, s); s = fmaf(a.w, b.w, s);
    }
#pragma unroll
    for (int m = 1; m < 64; m <<= 1) s += __shfl_xor(s, m, 64);
  }
  if (lane == 0) tgt[w] = s;
}

// ---------------- final scalar reduce --------------------------------------
__global__ __launch_bounds__(256)
void lce_finalize(const float* __restrict__ sumexp, const float* __restrict__ tgt,
                  const int* __restrict__ T, float* __restrict__ out) {
  int tid = threadIdx.x;
  float nll = 0.f, cnt = 0.f;
  for (int n = tid; n < N_ROWS; n += 256) {
    if (T[n] != IGN) {
      nll += logf(sumexp[n]) - tgt[n];
      cnt += 1.f;
    }
  }
#pragma unroll
  for (int m = 1; m < 64; m <<= 1) {
    nll += __shfl_xor(nll, m, 64);
    cnt += __shfl_xor(cnt, m, 64);
  }
  __shared__ float sn[4], sc[4];
  if ((tid & 63) == 0) { sn[tid >> 6] = nll; sc[tid >> 6] = cnt; }
  __syncthreads();
  if (tid == 0) {
    float a = 0.f, b = 0.f;
#pragma unroll
    for (int i = 0; i < 4; ++i) { a += sn[i]; b += sc[i]; }
    out[0] = a / fmaxf(b, 1.f);
  }
}

extern "C" void kernel_launch(void* const* d_in, const int* in_sizes, int n_in,
                              void* d_out, int out_size, void* d_ws, size_t ws_size,
                              hipStream_t stream) {
  const float* E = (const float*)d_in[0];
  const float* C = (const float*)d_in[1];
  const int*   T = (const int*)d_in[2];
  float* out = (float*)d_out;

  unsigned char* ws = (unsigned char*)d_ws;
  float* sumexp = (float*)ws;                        // 16 KB
  float* tgt    = (float*)(ws + 16384);              // 16 KB
  bf16_t* Ebf   = (bf16_t*)(ws + 32768);             // 16 MB
  bf16_t* Cbf   = (bf16_t*)(ws + 32768 + (size_t)N_ROWS * DIM * 2);

  const size_t need = 32768 + (size_t)N_ROWS * DIM * 2 + (size_t)VOCAB * DIM * 2;

  hipMemsetAsync(sumexp, 0, N_ROWS * sizeof(float), stream);

  if (ws_size >= need) {
    cvt_bf16<<<1024, 256, 0, stream>>>(E, Ebf, (long)N_ROWS * DIM / 8);
    cvt_bf16<<<4096, 256, 0, stream>>>(C, Cbf, (long)VOCAB * DIM / 8);
    lce_gemm_bf<<<dim3(N_ROWS / BM, VOCAB / BN), 256, 0, stream>>>(Ebf, Cbf, sumexp);
  } else {
    lce_gemm_f32<<<dim3(N_ROWS / BM, VOCAB / BN), FTHREADS, 65536, stream>>>(E, C, sumexp);
  }

  lce_tgt<<<dim3((N_ROWS * 64) / 256), 256, 0, stream>>>(E, C, T, tgt);
  lce_finalize<<<dim3(1), 256, 0, stream>>>(sumexp, tgt, T, out);
}

// Round 5
// 1124.462 us; speedup vs baseline: 5.4983x; 1.2288x over previous
//
#include <hip/hip_runtime.h>
#include <hip/hip_bf16.h>

typedef __bf16 bf16_t;
typedef bf16_t bf16x8 __attribute__((ext_vector_type(8)));
typedef float f32x4 __attribute__((ext_vector_type(4)));

#define N_ROWS 4096
#define DIM    2048
#define VOCAB  65536
#define IGN    (-100)

// ---------------- 256x256 8-phase GEMM ------------------------------------
#define BM 256
#define BN 256
#define BK 64
#define NT (DIM / BK)     // 32 K-tiles
#define NUNITS (4 * NT)   // 128 stage units (16KB each)

#define GLOAD_LDS16(gp, lp)                                                  \
  __builtin_amdgcn_global_load_lds(                                          \
      (const __attribute__((address_space(1))) void*)(gp),                   \
      (__attribute__((address_space(3))) void*)(lp), 16, 0, 0)

// fp32 -> bf16 pre-convert, 8 elems/thread/iter
__global__ __launch_bounds__(256)
void cvt_bf16(const float* __restrict__ src, bf16_t* __restrict__ dst, long n8) {
  long i = (long)blockIdx.x * 256 + threadIdx.x;
  long stride = (long)gridDim.x * 256;
  for (; i < n8; i += stride) {
    const float4* s = reinterpret_cast<const float4*>(src) + i * 2;
    float4 a = s[0], b = s[1];
    bf16x8 v = {(bf16_t)a.x, (bf16_t)a.y, (bf16_t)a.z, (bf16_t)a.w,
                (bf16_t)b.x, (bf16_t)b.y, (bf16_t)b.z, (bf16_t)b.w};
    *reinterpret_cast<bf16x8*>(dst + i * 8) = v;
  }
}

// 256x256 tile, BK=64, 8 waves (2M x 4N, each 128x64 out), 8-phase schedule.
// LDS 128KB = 2 buf x 4 units x 16KB. Unit u of K-tile t: u0=A[kcol 0:32],
// u1=B[kcol 0:32], u2=A[kcol 32:64], u3=B[kcol 32:64]; each [256 rows][32]
// packed 2 rows/128B line, swizzled: phys_sub = logical_sub ^ ((line&7)<<4).
// Phase (kk,nq): unit (kk*2) read only at nq=0 phase; unit (kk*2+1) read at
// both nq phases -> unit u dead after phase u. Stage unit H(4T+q+7) at tile T
// phase q (overwrites a dead region). vmcnt(6) once per tile guarantees
// tile T+1 fully landed (3 units = 6 loads in flight).
__global__ __launch_bounds__(512, 2)
void lce_gemm8(const bf16_t* __restrict__ Eb, const bf16_t* __restrict__ Cb,
               float* __restrict__ sumexp) {
  extern __shared__ unsigned char lds[];  // 131072
  const int tid = threadIdx.x;
  const int lane = tid & 63, wid = tid >> 6;
  const int wr = wid >> 2, wc = wid & 3;      // 2M x 4N waves
  const int l15 = lane & 15, lg = lane >> 4;

  // bijective XCD swizzle (nwg=4096, %8==0), row-tile fast for C reuse
  const int bid = blockIdx.x;
  const int wg = (bid & 7) * (((N_ROWS / BM) * (VOCAB / BN)) / 8) + (bid >> 3);
  const int brow = (wg & (N_ROWS / BM - 1)) * BM;
  const int bcol = (wg / (N_ROWS / BM)) * BN;

  // ---- staging precompute: per-thread 2 segments of 16B -------------------
  const int prel0 = (wid * 2) * 1024 + lane * 16;
  const int prel1 = (wid * 2 + 1) * 1024 + lane * 16;
  auto mkgoff = [&](int p) {
    int L = p >> 7, sub = p & 127;
    int sl = sub ^ ((L & 7) << 4);                  // inverse swizzle
    return (size_t)(L * 2 + (sl >> 6)) * DIM + (size_t)((sl & 63) >> 1);
  };
  const size_t goff0 = mkgoff(prel0), goff1 = mkgoff(prel1);

  const bf16_t* Ebase = Eb + (size_t)brow * DIM;
  const bf16_t* Cbase = Cb + (size_t)bcol * DIM;

  auto stage = [&](int ug) {   // ug = global unit index [0, NUNITS)
    const bf16_t* gb = ((ug & 1) ? Cbase : Ebase) +
                       (ug >> 2) * BK + ((ug >> 1) & 1) * 32;
    unsigned char* lb = lds + (ug & 7) * 16384;     // (buf*4 + u) * 16KB
    GLOAD_LDS16(gb + goff0, lb + prel0);
    GLOAD_LDS16(gb + goff1, lb + prel1);
  };

  // ---- fragment ds_read addresses (swizzled) ------------------------------
  const int lane_off = (((l15 & 1) << 6) | (lg << 4)) ^ ((l15 >> 1) << 4);
  const int abase = wr * 8192 + (l15 >> 1) * 128 + lane_off;
  const int bbase = 16384 + wc * 4096 + (l15 >> 1) * 128 + lane_off;

  f32x4 acc[8][4];
#pragma unroll
  for (int mi = 0; mi < 8; ++mi)
#pragma unroll
    for (int ni = 0; ni < 4; ++ni) acc[mi][ni] = (f32x4){0.f, 0.f, 0.f, 0.f};

  // ---- prologue: 7 units in flight, wait for first 4 (tile 0) -------------
  for (int h = 0; h < 7; ++h) stage(h);
  asm volatile("s_waitcnt vmcnt(6)" ::: "memory");
  __builtin_amdgcn_s_barrier();

  bf16x8 af[8], bf2[2];

  for (int T = 0; T < NT; ++T) {
    const unsigned char* base = lds + (T & 1) * 65536;
    const int ug0 = 4 * T + 7;
#pragma unroll
    for (int ph = 0; ph < 4; ++ph) {
      const int kk = ph >> 1, nq = ph & 1;
      const unsigned char* ab = base + kk * 32768;
      if (nq == 0) {
#pragma unroll
        for (int mi = 0; mi < 8; ++mi)
          af[mi] = *reinterpret_cast<const bf16x8*>(ab + abase + mi * 1024);
      }
#pragma unroll
      for (int t = 0; t < 2; ++t)
        bf2[t] = *reinterpret_cast<const bf16x8*>(ab + bbase + (nq * 2 + t) * 1024);
      const int ug = ug0 + ph;
      if (ug < NUNITS) stage(ug);
      if (ph == 3) {
        if (T < NT - 2) asm volatile("s_waitcnt vmcnt(6)" ::: "memory");
        else            asm volatile("s_waitcnt vmcnt(0)" ::: "memory");
      }
      __builtin_amdgcn_s_barrier();
      asm volatile("s_waitcnt lgkmcnt(0)" ::: "memory");
      __builtin_amdgcn_sched_barrier(0);
      __builtin_amdgcn_s_setprio(1);
#pragma unroll
      for (int mi = 0; mi < 8; ++mi)
#pragma unroll
        for (int t = 0; t < 2; ++t)
          acc[mi][nq * 2 + t] = __builtin_amdgcn_mfma_f32_16x16x32_bf16(
              af[mi], bf2[t], acc[mi][nq * 2 + t], 0, 0, 0);
      __builtin_amdgcn_s_setprio(0);
      __builtin_amdgcn_s_barrier();
    }
  }

  // ---- epilogue: per-row sum of exp over this block's 256 vocab cols ------
  // C/D: col = l15 (vocab), row = tile + wr*128 + mi*16 + lg*4 + j.
#pragma unroll
  for (int mi = 0; mi < 8; ++mi) {
    float p[4];
#pragma unroll
    for (int j = 0; j < 4; ++j) {
      p[j] = 0.f;
#pragma unroll
      for (int ni = 0; ni < 4; ++ni) p[j] += __expf(acc[mi][ni][j]);
    }
#pragma unroll
    for (int m = 1; m < 16; m <<= 1)
#pragma unroll
      for (int j = 0; j < 4; ++j) p[j] += __shfl_xor(p[j], m, 64);
    if (l15 == 0) {
      const int row = brow + wr * 128 + mi * 16 + lg * 4;
#pragma unroll
      for (int j = 0; j < 4; ++j) atomicAdd(&sumexp[row + j], p[j]);
    }
  }
}

// ---------------- fallback path (fp32 reg-staged, 128^2 tile) --------------
#define FBM 128
#define FBN 128
#define FBK 64
#define FNK (DIM / FBK)
#define FTHREADS 512

__global__ __launch_bounds__(FTHREADS, 4)
void lce_gemm_f32(const float* __restrict__ E, const float* __restrict__ C,
                  float* __restrict__ sumexp) {
  extern __shared__ unsigned char lds[];
  const int tid  = threadIdx.x;
  const int brow = blockIdx.x * FBM;
  const int bcol = blockIdx.y * FBN;

  float4 ra[4], rb[4];
  auto ld = [&](int k0) {
#pragma unroll
    for (int i = 0; i < 4; ++i) {
      int f = tid + i * FTHREADS;
      int r = f >> 4;
      int c = (f & 15) << 2;
      ra[i] = *reinterpret_cast<const float4*>(&E[(size_t)(brow + r) * DIM + k0 + c]);
      rb[i] = *reinterpret_cast<const float4*>(&C[(size_t)(bcol + r) * DIM + k0 + c]);
    }
  };
  auto st = [&](int buf) {
    unsigned char* a = lds + buf * 32768;
    unsigned char* b = a + 16384;
#pragma unroll
    for (int i = 0; i < 4; ++i) {
      int f  = tid + i * FTHREADS;
      int r  = f >> 4;
      int cbb = (f & 15) << 3;
      int off = r * 128 + (cbb ^ ((r & 7) << 4));
      union { bf16_t h[4]; unsigned long long u; } pa, pb;
      pa.h[0] = (bf16_t)ra[i].x; pa.h[1] = (bf16_t)ra[i].y;
      pa.h[2] = (bf16_t)ra[i].z; pa.h[3] = (bf16_t)ra[i].w;
      pb.h[0] = (bf16_t)rb[i].x; pb.h[1] = (bf16_t)rb[i].y;
      pb.h[2] = (bf16_t)rb[i].z; pb.h[3] = (bf16_t)rb[i].w;
      *reinterpret_cast<unsigned long long*>(a + off) = pa.u;
      *reinterpret_cast<unsigned long long*>(b + off) = pb.u;
    }
  };

  f32x4 acc[4][2];
#pragma unroll
  for (int mi = 0; mi < 4; ++mi)
#pragma unroll
    for (int ni = 0; ni < 2; ++ni) acc[mi][ni] = (f32x4){0.f, 0.f, 0.f, 0.f};

  const int lane = tid & 63, wid = tid >> 6;
  const int wr = wid >> 2, wc = wid & 3;
  const int l15 = lane & 15, lg = lane >> 4;
  const int swz = (l15 & 7) << 4;

  auto comp = [&](int buf) {
    const unsigned char* a = lds + buf * 32768;
    const unsigned char* b = a + 16384;
#pragma unroll
    for (int kk = 0; kk < 2; ++kk) {
      const int cbase = (kk * 64 + lg * 16) ^ swz;
      bf16x8 af[4], bfr[2];
#pragma unroll
      for (int mi = 0; mi < 4; ++mi)
        af[mi] = *reinterpret_cast<const bf16x8*>(
            a + (wr * 64 + mi * 16 + l15) * 128 + cbase);
#pragma unroll
      for (int ni = 0; ni < 2; ++ni)
        bfr[ni] = *reinterpret_cast<const bf16x8*>(
            b + (wc * 32 + ni * 16 + l15) * 128 + cbase);
#pragma unroll
      for (int mi = 0; mi < 4; ++mi)
#pragma unroll
        for (int ni = 0; ni < 2; ++ni)
          acc[mi][ni] = __builtin_amdgcn_mfma_f32_16x16x32_bf16(
              af[mi], bfr[ni], acc[mi][ni], 0, 0, 0);
    }
  };

  ld(0);
  st(0);
  for (int kt = 0; kt < FNK; ++kt) {
    __syncthreads();
    if (kt + 1 < FNK) ld((kt + 1) * FBK);
    comp(kt & 1);
    if (kt + 1 < FNK) st((kt + 1) & 1);
  }

#pragma unroll
  for (int mi = 0; mi < 4; ++mi) {
    float p[4];
#pragma unroll
    for (int j = 0; j < 4; ++j)
      p[j] = __expf(acc[mi][0][j]) + __expf(acc[mi][1][j]);
#pragma unroll
    for (int m = 1; m < 16; m <<= 1)
#pragma unroll
      for (int j = 0; j < 4; ++j) p[j] += __shfl_xor(p[j], m, 64);
    if (l15 == 0) {
      int row = brow + wr * 64 + mi * 16 + lg * 4;
#pragma unroll
      for (int j = 0; j < 4; ++j) atomicAdd(&sumexp[row + j], p[j]);
    }
  }
}

// ---------------- exact fp32 target logit, one wave per row ----------------
__global__ __launch_bounds__(256)
void lce_tgt(const float* __restrict__ E, const float* __restrict__ C,
             const int* __restrict__ T, float* __restrict__ tgt) {
  int w = (int)((blockIdx.x * blockDim.x + threadIdx.x) >> 6);
  int lane = threadIdx.x & 63;
  if (w >= N_ROWS) return;
  int t = T[w];
  float s = 0.f;
  if (t != IGN) {
    const float4* er = reinterpret_cast<const float4*>(E + (size_t)w * DIM);
    const float4* cr = reinterpret_cast<const float4*>(C + (size_t)t * DIM);
#pragma unroll
    for (int i = 0; i < DIM / 4 / 64; ++i) {
      float4 a = er[lane + i * 64];
      float4 b = cr[lane + i * 64];
      s = fmaf(a.x, b.x, s); s = fmaf(a.y, b.y, s);
      s = fmaf(a.z, b.z, s); s = fmaf(a.w, b.w, s);
    }
#pragma unroll
    for (int m = 1; m < 64; m <<= 1) s += __shfl_xor(s, m, 64);
  }
  if (lane == 0) tgt[w] = s;
}

// ---------------- final scalar reduce --------------------------------------
__global__ __launch_bounds__(256)
void lce_finalize(const float* __restrict__ sumexp, const float* __restrict__ tgt,
                  const int* __restrict__ T, float* __restrict__ out) {
  int tid = threadIdx.x;
  float nll = 0.f, cnt = 0.f;
  for (int n = tid; n < N_ROWS; n += 256) {
    if (T[n] != IGN) {
      nll += logf(sumexp[n]) - tgt[n];
      cnt += 1.f;
    }
  }
#pragma unroll
  for (int m = 1; m < 64; m <<= 1) {
    nll += __shfl_xor(nll, m, 64);
    cnt += __shfl_xor(cnt, m, 64);
  }
  __shared__ float sn[4], sc[4];
  if ((tid & 63) == 0) { sn[tid >> 6] = nll; sc[tid >> 6] = cnt; }
  __syncthreads();
  if (tid == 0) {
    float a = 0.f, b = 0.f;
#pragma unroll
    for (int i = 0; i < 4; ++i) { a += sn[i]; b += sc[i]; }
    out[0] = a / fmaxf(b, 1.f);
  }
}

extern "C" void kernel_launch(void* const* d_in, const int* in_sizes, int n_in,
                              void* d_out, int out_size, void* d_ws, size_t ws_size,
                              hipStream_t stream) {
  const float* E = (const float*)d_in[0];
  const float* C = (const float*)d_in[1];
  const int*   T = (const int*)d_in[2];
  float* out = (float*)d_out;

  unsigned char* ws = (unsigned char*)d_ws;
  float* sumexp = (float*)ws;                        // 16 KB
  float* tgt    = (float*)(ws + 16384);              // 16 KB
  bf16_t* Ebf   = (bf16_t*)(ws + 32768);             // 16 MB
  bf16_t* Cbf   = (bf16_t*)(ws + 32768 + (size_t)N_ROWS * DIM * 2);

  const size_t need = 32768 + (size_t)N_ROWS * DIM * 2 + (size_t)VOCAB * DIM * 2;

  hipMemsetAsync(sumexp, 0, N_ROWS * sizeof(float), stream);

  if (ws_size >= need) {
    cvt_bf16<<<1024, 256, 0, stream>>>(E, Ebf, (long)N_ROWS * DIM / 8);
    cvt_bf16<<<4096, 256, 0, stream>>>(C, Cbf, (long)VOCAB * DIM / 8);
    lce_gemm8<<<dim3((N_ROWS / BM) * (VOCAB / BN)), 512, 131072, stream>>>(Ebf, Cbf, sumexp);
  } else {
    lce_gemm_f32<<<dim3(N_ROWS / FBM, VOCAB / FBN), FTHREADS, 65536, stream>>>(E, C, sumexp);
  }

  lce_tgt<<<dim3((N_ROWS * 64) / 256), 256, 0, stream>>>(E, C, T, tgt);
  lce_finalize<<<dim3(1), 256, 0, stream>>>(sumexp, tgt, T, out);
}

// Round 6
// 1094.007 us; speedup vs baseline: 5.6513x; 1.0278x over previous
//
#include <hip/hip_runtime.h>
#include <hip/hip_bf16.h>

typedef __bf16 bf16_t;
typedef bf16_t bf16x8 __attribute__((ext_vector_type(8)));
typedef float f32x4 __attribute__((ext_vector_type(4)));

#define N_ROWS 4096
#define DIM    2048
#define VOCAB  65536
#define IGN    (-100)

// ---------------- 256x256 8-phase GEMM ------------------------------------
#define BM 256
#define BN 256
#define BK 64
#define NT (DIM / BK)     // 32 K-tiles
#define NUNITS (4 * NT)   // 128 stage units (16KB each)

#define GLOAD_LDS16(gp, lp)                                                  \
  __builtin_amdgcn_global_load_lds(                                          \
      (const __attribute__((address_space(1))) void*)(gp),                   \
      (__attribute__((address_space(3))) void*)(lp), 16, 0, 0)

// fp32 -> bf16 pre-convert, 8 elems/thread/iter
__global__ __launch_bounds__(256)
void cvt_bf16(const float* __restrict__ src, bf16_t* __restrict__ dst, long n8) {
  long i = (long)blockIdx.x * 256 + threadIdx.x;
  long stride = (long)gridDim.x * 256;
  for (; i < n8; i += stride) {
    const float4* s = reinterpret_cast<const float4*>(src) + i * 2;
    float4 a = s[0], b = s[1];
    bf16x8 v = {(bf16_t)a.x, (bf16_t)a.y, (bf16_t)a.z, (bf16_t)a.w,
                (bf16_t)b.x, (bf16_t)b.y, (bf16_t)b.z, (bf16_t)b.w};
    *reinterpret_cast<bf16x8*>(dst + i * 8) = v;
  }
}

// 256x256 tile, BK=64, 8 waves (2M x 4N, each 128x64 out), 4-phase/K-tile.
// LDS 128KB = 8 slots x 16KB (2 logical buffers). Unit u of tile t:
// u0=A[k 0:32], u1=B[k 0:32], u2=A[k 32:64], u3=B[k 32:64]; each [256r][32c]
// packed 2 rows/128B line, swizzle phys_sub = sub ^ ((line&7)<<4).
// ALL 24 ds_reads of a tile issue at tile top (data guaranteed by prev
// vmcnt(6)+barrier); phases wait counted lgkmcnt {12,12,0,0}; issue order
// {A0,B0} | {A1,B1} pinned by sched_barrier. One barrier per phase.
// Slot lifetime: A0 slot overwritten by ph1 stage (reads drained ph0),
// B0 by ph2 (drained ph1), A1 by ph3 (drained ph2), B1 by next ph0 (ph3).
__global__ __launch_bounds__(512, 2)
void lce_gemm8(const bf16_t* __restrict__ Eb, const bf16_t* __restrict__ Cb,
               float* __restrict__ sumexp) {
  extern __shared__ unsigned char lds[];  // 131072
  const int tid = threadIdx.x;
  const int lane = tid & 63, wid = tid >> 6;
  const int wr = wid >> 2, wc = wid & 3;      // 2M x 4N waves
  const int l15 = lane & 15, lg = lane >> 4;

  // bijective XCD swizzle (nwg=4096, %8==0), row-tile fast for C reuse
  const int bid = blockIdx.x;
  const int wg = (bid & 7) * (((N_ROWS / BM) * (VOCAB / BN)) / 8) + (bid >> 3);
  const int brow = (wg & (N_ROWS / BM - 1)) * BM;
  const int bcol = (wg / (N_ROWS / BM)) * BN;

  // ---- staging precompute: per-thread 2 segments of 16B -------------------
  const int prel0 = (wid * 2) * 1024 + lane * 16;
  const int prel1 = (wid * 2 + 1) * 1024 + lane * 16;
  auto mkgoff = [&](int p) {
    int L = p >> 7, sub = p & 127;
    int sl = sub ^ ((L & 7) << 4);                  // inverse swizzle
    return (size_t)(L * 2 + (sl >> 6)) * DIM + (size_t)((sl & 63) >> 1);
  };
  const size_t goff0 = mkgoff(prel0), goff1 = mkgoff(prel1);

  const bf16_t* Ebase = Eb + (size_t)brow * DIM;
  const bf16_t* Cbase = Cb + (size_t)bcol * DIM;

  auto stage = [&](int ug) {   // ug = global unit index [0, NUNITS)
    const bf16_t* gb = ((ug & 1) ? Cbase : Ebase) +
                       (ug >> 2) * BK + ((ug >> 1) & 1) * 32;
    unsigned char* lb = lds + (ug & 7) * 16384;     // slot = ug mod 8
    GLOAD_LDS16(gb + goff0, lb + prel0);
    GLOAD_LDS16(gb + goff1, lb + prel1);
  };

  // ---- fragment ds_read addresses (swizzled) ------------------------------
  const int lane_off = (((l15 & 1) << 6) | (lg << 4)) ^ ((l15 >> 1) << 4);
  const int abase = wr * 8192 + (l15 >> 1) * 128 + lane_off;
  const int bbase = 16384 + wc * 4096 + (l15 >> 1) * 128 + lane_off;

  f32x4 acc[8][4];
#pragma unroll
  for (int mi = 0; mi < 8; ++mi)
#pragma unroll
    for (int ni = 0; ni < 4; ++ni) acc[mi][ni] = (f32x4){0.f, 0.f, 0.f, 0.f};

  // ---- prologue: 7 units in flight, wait for first 4 (tile 0) -------------
  for (int h = 0; h < 7; ++h) stage(h);
  asm volatile("s_waitcnt vmcnt(6)" ::: "memory");
  __builtin_amdgcn_s_barrier();

  bf16x8 af[2][8], bfr[2][4];

  for (int T = 0; T < NT; ++T) {
    const unsigned char* base = lds + (T & 1) * 65536;
    const int ug0 = 4 * T + 7;

    // tile-top: issue all 24 ds_reads; order {A0,B0} then {A1,B1}
#pragma unroll
    for (int kk = 0; kk < 2; ++kk) {
      const unsigned char* ab = base + kk * 32768;
#pragma unroll
      for (int mi = 0; mi < 8; ++mi)
        af[kk][mi] = *reinterpret_cast<const bf16x8*>(ab + abase + mi * 1024);
#pragma unroll
      for (int t = 0; t < 4; ++t)
        bfr[kk][t] = *reinterpret_cast<const bf16x8*>(ab + bbase + t * 1024);
      __builtin_amdgcn_sched_barrier(0);            // pin issue order
    }

#pragma unroll
    for (int ph = 0; ph < 4; ++ph) {
      const int kk = ph >> 1, nq = ph & 1;
      const int ug = ug0 + ph;
      if (ug < NUNITS) stage(ug);
      if (ph == 3) {
        if (T < NT - 2) asm volatile("s_waitcnt vmcnt(6)" ::: "memory");
        else            asm volatile("s_waitcnt vmcnt(0)" ::: "memory");
      }
      if (ph < 2) asm volatile("s_waitcnt lgkmcnt(12)" ::: "memory");
      else        asm volatile("s_waitcnt lgkmcnt(0)" ::: "memory");
      __builtin_amdgcn_sched_barrier(0);
      __builtin_amdgcn_s_setprio(1);
#pragma unroll
      for (int mi = 0; mi < 8; ++mi)
#pragma unroll
        for (int t = 0; t < 2; ++t)
          acc[mi][nq * 2 + t] = __builtin_amdgcn_mfma_f32_16x16x32_bf16(
              af[kk][mi], bfr[kk][nq * 2 + t], acc[mi][nq * 2 + t], 0, 0, 0);
      __builtin_amdgcn_s_setprio(0);
      __builtin_amdgcn_s_barrier();
    }
  }

  // ---- epilogue: per-row sum of exp over this block's 256 vocab cols ------
  // C/D: col = l15 (vocab), row = brow + wr*128 + mi*16 + lg*4 + j.
#pragma unroll
  for (int mi = 0; mi < 8; ++mi) {
    float p[4];
#pragma unroll
    for (int j = 0; j < 4; ++j) {
      p[j] = 0.f;
#pragma unroll
      for (int ni = 0; ni < 4; ++ni) p[j] += __expf(acc[mi][ni][j]);
    }
#pragma unroll
    for (int m = 1; m < 16; m <<= 1)
#pragma unroll
      for (int j = 0; j < 4; ++j) p[j] += __shfl_xor(p[j], m, 64);
    if (l15 == 0) {
      const int row = brow + wr * 128 + mi * 16 + lg * 4;
#pragma unroll
      for (int j = 0; j < 4; ++j) atomicAdd(&sumexp[row + j], p[j]);
    }
  }
}

// ---------------- fallback path (fp32 reg-staged, 128^2 tile) --------------
#define FBM 128
#define FBN 128
#define FBK 64
#define FNK (DIM / FBK)
#define FTHREADS 512

__global__ __launch_bounds__(FTHREADS, 4)
void lce_gemm_f32(const float* __restrict__ E, const float* __restrict__ C,
                  float* __restrict__ sumexp) {
  extern __shared__ unsigned char lds[];
  const int tid  = threadIdx.x;
  const int brow = blockIdx.x * FBM;
  const int bcol = blockIdx.y * FBN;

  float4 ra[4], rb[4];
  auto ld = [&](int k0) {
#pragma unroll
    for (int i = 0; i < 4; ++i) {
      int f = tid + i * FTHREADS;
      int r = f >> 4;
      int c = (f & 15) << 2;
      ra[i] = *reinterpret_cast<const float4*>(&E[(size_t)(brow + r) * DIM + k0 + c]);
      rb[i] = *reinterpret_cast<const float4*>(&C[(size_t)(bcol + r) * DIM + k0 + c]);
    }
  };
  auto st = [&](int buf) {
    unsigned char* a = lds + buf * 32768;
    unsigned char* b = a + 16384;
#pragma unroll
    for (int i = 0; i < 4; ++i) {
      int f  = tid + i * FTHREADS;
      int r  = f >> 4;
      int cbb = (f & 15) << 3;
      int off = r * 128 + (cbb ^ ((r & 7) << 4));
      union { bf16_t h[4]; unsigned long long u; } pa, pb;
      pa.h[0] = (bf16_t)ra[i].x; pa.h[1] = (bf16_t)ra[i].y;
      pa.h[2] = (bf16_t)ra[i].z; pa.h[3] = (bf16_t)ra[i].w;
      pb.h[0] = (bf16_t)rb[i].x; pb.h[1] = (bf16_t)rb[i].y;
      pb.h[2] = (bf16_t)rb[i].z; pb.h[3] = (bf16_t)rb[i].w;
      *reinterpret_cast<unsigned long long*>(a + off) = pa.u;
      *reinterpret_cast<unsigned long long*>(b + off) = pb.u;
    }
  };

  f32x4 acc[4][2];
#pragma unroll
  for (int mi = 0; mi < 4; ++mi)
#pragma unroll
    for (int ni = 0; ni < 2; ++ni) acc[mi][ni] = (f32x4){0.f, 0.f, 0.f, 0.f};

  const int lane = tid & 63, wid = tid >> 6;
  const int wr = wid >> 2, wc = wid & 3;
  const int l15 = lane & 15, lg = lane >> 4;
  const int swz = (l15 & 7) << 4;

  auto comp = [&](int buf) {
    const unsigned char* a = lds + buf * 32768;
    const unsigned char* b = a + 16384;
#pragma unroll
    for (int kk = 0; kk < 2; ++kk) {
      const int cbase = (kk * 64 + lg * 16) ^ swz;
      bf16x8 af[4], bfr[2];
#pragma unroll
      for (int mi = 0; mi < 4; ++mi)
        af[mi] = *reinterpret_cast<const bf16x8*>(
            a + (wr * 64 + mi * 16 + l15) * 128 + cbase);
#pragma unroll
      for (int ni = 0; ni < 2; ++ni)
        bfr[ni] = *reinterpret_cast<const bf16x8*>(
            b + (wc * 32 + ni * 16 + l15) * 128 + cbase);
#pragma unroll
      for (int mi = 0; mi < 4; ++mi)
#pragma unroll
        for (int ni = 0; ni < 2; ++ni)
          acc[mi][ni] = __builtin_amdgcn_mfma_f32_16x16x32_bf16(
              af[mi], bfr[ni], acc[mi][ni], 0, 0, 0);
    }
  };

  ld(0);
  st(0);
  for (int kt = 0; kt < FNK; ++kt) {
    __syncthreads();
    if (kt + 1 < FNK) ld((kt + 1) * FBK);
    comp(kt & 1);
    if (kt + 1 < FNK) st((kt + 1) & 1);
  }

#pragma unroll
  for (int mi = 0; mi < 4; ++mi) {
    float p[4];
#pragma unroll
    for (int j = 0; j < 4; ++j)
      p[j] = __expf(acc[mi][0][j]) + __expf(acc[mi][1][j]);
#pragma unroll
    for (int m = 1; m < 16; m <<= 1)
#pragma unroll
      for (int j = 0; j < 4; ++j) p[j] += __shfl_xor(p[j], m, 64);
    if (l15 == 0) {
      int row = brow + wr * 64 + mi * 16 + lg * 4;
#pragma unroll
      for (int j = 0; j < 4; ++j) atomicAdd(&sumexp[row + j], p[j]);
    }
  }
}

// ---------------- exact fp32 target logit, one wave per row ----------------
__global__ __launch_bounds__(256)
void lce_tgt(const float* __restrict__ E, const float* __restrict__ C,
             const int* __restrict__ T, float* __restrict__ tgt) {
  int w = (int)((blockIdx.x * blockDim.x + threadIdx.x) >> 6);
  int lane = threadIdx.x & 63;
  if (w >= N_ROWS) return;
  int t = T[w];
  float s = 0.f;
  if (t != IGN) {
    const float4* er = reinterpret_cast<const float4*>(E + (size_t)w * DIM);
    const float4* cr = reinterpret_cast<const float4*>(C + (size_t)t * DIM);
#pragma unroll
    for (int i = 0; i < DIM / 4 / 64; ++i) {
      float4 a = er[lane + i * 64];
      float4 b = cr[lane + i * 64];
      s = fmaf(a.x, b.x, s); s = fmaf(a.y, b.y, s);
      s = fmaf(a.z, b.z, s); s = fmaf(a.w, b.w, s);
    }
#pragma unroll
    for (int m = 1; m < 64; m <<= 1) s += __shfl_xor(s, m, 64);
  }
  if (lane == 0) tgt[w] = s;
}

// ---------------- final scalar reduce --------------------------------------
__global__ __launch_bounds__(256)
void lce_finalize(const float* __restrict__ sumexp, const float* __restrict__ tgt,
                  const int* __restrict__ T, float* __restrict__ out) {
  int tid = threadIdx.x;
  float nll = 0.f, cnt = 0.f;
  for (int n = tid; n < N_ROWS; n += 256) {
    if (T[n] != IGN) {
      nll += logf(sumexp[n]) - tgt[n];
      cnt += 1.f;
    }
  }
#pragma unroll
  for (int m = 1; m < 64; m <<= 1) {
    nll += __shfl_xor(nll, m, 64);
    cnt += __shfl_xor(cnt, m, 64);
  }
  __shared__ float sn[4], sc[4];
  if ((tid & 63) == 0) { sn[tid >> 6] = nll; sc[tid >> 6] = cnt; }
  __syncthreads();
  if (tid == 0) {
    float a = 0.f, b = 0.f;
#pragma unroll
    for (int i = 0; i < 4; ++i) { a += sn[i]; b += sc[i]; }
    out[0] = a / fmaxf(b, 1.f);
  }
}

extern "C" void kernel_launch(void* const* d_in, const int* in_sizes, int n_in,
                              void* d_out, int out_size, void* d_ws, size_t ws_size,
                              hipStream_t stream) {
  const float* E = (const float*)d_in[0];
  const float* C = (const float*)d_in[1];
  const int*   T = (const int*)d_in[2];
  float* out = (float*)d_out;

  unsigned char* ws = (unsigned char*)d_ws;
  float* sumexp = (float*)ws;                        // 16 KB
  float* tgt    = (float*)(ws + 16384);              // 16 KB
  bf16_t* Ebf   = (bf16_t*)(ws + 32768);             // 16 MB
  bf16_t* Cbf   = (bf16_t*)(ws + 32768 + (size_t)N_ROWS * DIM * 2);

  const size_t need = 32768 + (size_t)N_ROWS * DIM * 2 + (size_t)VOCAB * DIM * 2;

  hipMemsetAsync(sumexp, 0, N_ROWS * sizeof(float), stream);

  if (ws_size >= need) {
    cvt_bf16<<<1024, 256, 0, stream>>>(E, Ebf, (long)N_ROWS * DIM / 8);
    cvt_bf16<<<4096, 256, 0, stream>>>(C, Cbf, (long)VOCAB * DIM / 8);
    lce_gemm8<<<dim3((N_ROWS / BM) * (VOCAB / BN)), 512, 131072, stream>>>(Ebf, Cbf, sumexp);
  } else {
    lce_gemm_f32<<<dim3(N_ROWS / FBM, VOCAB / FBN), FTHREADS, 65536, stream>>>(E, C, sumexp);
  }

  lce_tgt<<<dim3((N_ROWS * 64) / 256), 256, 0, stream>>>(E, C, T, tgt);
  lce_finalize<<<dim3(1), 256, 0, stream>>>(sumexp, tgt, T, out);
}